// Round 3
// baseline (497.140 us; speedup 1.0000x reference)
//
#include <hip/hip_runtime.h>
#include <math.h>

// Problem constants
#define BB 32
#define CC 256
#define HH 64
#define WW 64
#define NN 4096   // H*W

__inline__ __device__ float waveReduceSum(float v) {
    #pragma unroll
    for (int off = 32; off > 0; off >>= 1) v += __shfl_xor(v, off);
    return v;
}
__inline__ __device__ float waveReduceMax(float v) {
    #pragma unroll
    for (int off = 32; off > 0; off >>= 1) v = fmaxf(v, __shfl_xor(v, off));
    return v;
}

// ---------------------------------------------------------------------------
// Kernel 1: per-(b,c) plane prep. ONE pass over F:
//   - sum (-> mean -> a = sigmoid(mean))
//   - sum of squares (-> inv_norm = 1/(sqrt(ssq)+1e-6))
//   - max (-> binarize F >= 0.6*max)
//   - 5x5 count_include_pad avg-pool on the binary mask, zero padding:
//       density >= 0.5  <=>  integer window count >= 13  (12/25<0.5<13/25)
//   - d = fraction of pixels passing; s = sqrt(a)*sqrt(d)
// ---------------------------------------------------------------------------
__global__ __launch_bounds__(256) void k_prep(const float* __restrict__ F,
                                              float* __restrict__ inv_norm,
                                              float* __restrict__ s_score) {
    const int plane = blockIdx.x;                 // b*256 + c
    const int tid = threadIdx.x;
    __shared__ float bin[4096];
    __shared__ float rowsum[4096];
    __shared__ float swS[4], swQ[4], swM[4];

    const float4* src = (const float4*)(F + (size_t)plane * NN);
    float4 v[4];
    float sum = 0.f, ssq = 0.f, mx = -INFINITY;
    #pragma unroll
    for (int q = 0; q < 4; ++q) {
        v[q] = src[tid + q * 256];
        sum += v[q].x + v[q].y + v[q].z + v[q].w;
        ssq += v[q].x * v[q].x + v[q].y * v[q].y + v[q].z * v[q].z + v[q].w * v[q].w;
        mx = fmaxf(mx, fmaxf(fmaxf(v[q].x, v[q].y), fmaxf(v[q].z, v[q].w)));
    }
    sum = waveReduceSum(sum);
    ssq = waveReduceSum(ssq);
    mx  = waveReduceMax(mx);
    const int w = tid >> 6, ln = tid & 63;
    if (ln == 0) { swS[w] = sum; swQ[w] = ssq; swM[w] = mx; }
    __syncthreads();
    if (tid == 0) {
        swS[0] = swS[0] + swS[1] + swS[2] + swS[3];
        swQ[0] = swQ[0] + swQ[1] + swQ[2] + swQ[3];
        swM[0] = fmaxf(fmaxf(swM[0], swM[1]), fmaxf(swM[2], swM[3]));
    }
    __syncthreads();
    const float totsum = swS[0];
    const float totssq = swQ[0];
    const float thr = 0.6f * swM[0];

    // binarize into LDS
    #pragma unroll
    for (int q = 0; q < 4; ++q) {
        const int base = (tid + q * 256) * 4;
        bin[base + 0] = (v[q].x >= thr) ? 1.f : 0.f;
        bin[base + 1] = (v[q].y >= thr) ? 1.f : 0.f;
        bin[base + 2] = (v[q].z >= thr) ? 1.f : 0.f;
        bin[base + 3] = (v[q].w >= thr) ? 1.f : 0.f;
    }
    __syncthreads();

    // horizontal 5-window sum (zero pad)
    #pragma unroll
    for (int q = 0; q < 16; ++q) {
        const int p = tid + q * 256;
        const int h = p >> 6, x = p & 63;
        float s5 = 0.f;
        #pragma unroll
        for (int dw = -2; dw <= 2; ++dw) {
            const int xx = x + dw;
            if (xx >= 0 && xx < 64) s5 += bin[h * 64 + xx];
        }
        rowsum[p] = s5;
    }
    __syncthreads();

    // vertical 5-window sum + threshold count
    int cge = 0;
    #pragma unroll
    for (int q = 0; q < 16; ++q) {
        const int p = tid + q * 256;
        const int h = p >> 6, x = p & 63;
        float cnt = 0.f;
        #pragma unroll
        for (int dh = -2; dh <= 2; ++dh) {
            const int hh = h + dh;
            if (hh >= 0 && hh < 64) cnt += rowsum[hh * 64 + x];
        }
        if (cnt >= 12.5f) cge++;   // density >= 0.5 exactly (integer counts)
    }
    float cf = waveReduceSum((float)cge);
    __syncthreads();
    if (ln == 0) swS[w] = cf;
    __syncthreads();
    if (tid == 0) {
        const float total = swS[0] + swS[1] + swS[2] + swS[3];
        const float d = total / 4096.f;                      // exact
        const float a = 1.f / (1.f + expf(-(totsum / 4096.f)));
        s_score[plane] = sqrtf(a) * sqrtf(d);
        inv_norm[plane] = 1.f / (sqrtf(totssq) + 1e-6f);
    }
}

// ---------------------------------------------------------------------------
// Kernel 2: gram partials. S_batch = mean_b( Fn_b @ Fn_b^T ), Fn rows
// normalized by 1/(norm+1e-6). Symmetry: only 10 upper 64x64 tiles.
// Split-K: per (b, half) -> K chunk of 2048. fp32 vector FMA GEMM,
// two-level fp32 accumulation (stage-local L1 -> L2) for accuracy.
// Output: S_part[(b*2+chunk)*10 + t][64][64] f32.
// ---------------------------------------------------------------------------
__global__ __launch_bounds__(256) void k_gram(const float* __restrict__ F,
                                              const float* __restrict__ inv_norm,
                                              float* __restrict__ S_part) {
    static const int TI[10] = {0,0,0,0,1,1,1,2,2,3};
    static const int TJ[10] = {0,1,2,3,1,2,3,2,3,3};
    const int t  = blockIdx.x;       // 0..9 tile
    const int bc = blockIdx.y;       // 0..63 = b*2 + chunk
    const int b = bc >> 1, chunk = bc & 1;
    const int ti = TI[t], tj = TJ[t];
    const int k0 = chunk * 2048;

    __shared__ float As[32][68];     // [kk][row], pad to 68 -> conflict-light
    __shared__ float Bs[32][68];

    const int tid = threadIdx.x;
    const int lrow = tid >> 2;       // 0..63
    const int kgrp = tid & 3;        // 0..3 (8 floats each)
    const float* Fb = F + (size_t)b * CC * NN;
    const float scaleA = inv_norm[b * CC + ti * 64 + lrow];
    const float scaleB = inv_norm[b * CC + tj * 64 + lrow];
    const float* gA = Fb + (size_t)(ti * 64 + lrow) * NN + k0 + kgrp * 8;
    const float* gB = Fb + (size_t)(tj * 64 + lrow) * NN + k0 + kgrp * 8;

    const int r0 = (tid >> 4) << 2;  // row quad
    const int c0 = (tid & 15) << 2;  // col quad

    float accL2[16];
    #pragma unroll
    for (int e = 0; e < 16; ++e) accL2[e] = 0.f;

    for (int s = 0; s < 64; ++s) {
        const float4 a0 = *(const float4*)(gA);
        const float4 a1 = *(const float4*)(gA + 4);
        const float4 b0 = *(const float4*)(gB);
        const float4 b1 = *(const float4*)(gB + 4);
        __syncthreads();
        const int kb = kgrp * 8;
        As[kb + 0][lrow] = a0.x * scaleA; As[kb + 1][lrow] = a0.y * scaleA;
        As[kb + 2][lrow] = a0.z * scaleA; As[kb + 3][lrow] = a0.w * scaleA;
        As[kb + 4][lrow] = a1.x * scaleA; As[kb + 5][lrow] = a1.y * scaleA;
        As[kb + 6][lrow] = a1.z * scaleA; As[kb + 7][lrow] = a1.w * scaleA;
        Bs[kb + 0][lrow] = b0.x * scaleB; Bs[kb + 1][lrow] = b0.y * scaleB;
        Bs[kb + 2][lrow] = b0.z * scaleB; Bs[kb + 3][lrow] = b0.w * scaleB;
        Bs[kb + 4][lrow] = b1.x * scaleB; Bs[kb + 5][lrow] = b1.y * scaleB;
        Bs[kb + 6][lrow] = b1.z * scaleB; Bs[kb + 7][lrow] = b1.w * scaleB;
        __syncthreads();

        float accL1[16];
        #pragma unroll
        for (int e = 0; e < 16; ++e) accL1[e] = 0.f;
        #pragma unroll
        for (int kk = 0; kk < 32; ++kk) {
            const float4 av = *(const float4*)&As[kk][r0];
            const float4 bv = *(const float4*)&Bs[kk][c0];
            const float ar[4] = {av.x, av.y, av.z, av.w};
            const float br[4] = {bv.x, bv.y, bv.z, bv.w};
            #pragma unroll
            for (int rr = 0; rr < 4; ++rr)
                #pragma unroll
                for (int cc = 0; cc < 4; ++cc)
                    accL1[rr * 4 + cc] += ar[rr] * br[cc];
        }
        #pragma unroll
        for (int e = 0; e < 16; ++e) accL2[e] += accL1[e];
        gA += 32; gB += 32;
    }

    float* dst = S_part + (size_t)(bc * 10 + t) * 4096;
    #pragma unroll
    for (int rr = 0; rr < 4; ++rr)
        #pragma unroll
        for (int cc = 0; cc < 4; ++cc)
            dst[(r0 + rr) * 64 + (c0 + cc)] = accL2[rr * 4 + cc];
}

// ---------------------------------------------------------------------------
// Kernel 3: reduce partials (f64, deterministic), EMA, symmetrize.
// ---------------------------------------------------------------------------
__global__ __launch_bounds__(256) void k_snew(const float* __restrict__ S_part,
                                              const float* __restrict__ S_old,
                                              float* __restrict__ S_new) {
    const int c = blockIdx.x;
    const int d = threadIdx.x;
    if (d < c) return;   // upper triangle incl diagonal
    static const int tmap[16] = {0,1,2,3, -1,4,5,6, -1,-1,7,8, -1,-1,-1,9};
    const int t = tmap[((c >> 6) << 2) | (d >> 6)];
    const int r = c & 63, col = d & 63;
    const float* base = S_part + (size_t)t * 4096 + r * 64 + col;
    double sum = 0.0;
    for (int p = 0; p < 64; ++p) sum += (double)base[(size_t)p * 40960];
    const float sb = (float)(sum * (1.0 / 32.0));   // mean over B=32
    S_new[c * 256 + d] = 0.999f * S_old[c * 256 + d] + 0.001f * sb;
    if (d != c)
        S_new[d * 256 + c] = 0.999f * S_old[d * 256 + c] + 0.001f * sb;
}

// ---------------------------------------------------------------------------
// Kernel 4: per-sample mask + permutation. One block per b.
// Replicates: prob = sigmoid(5*(s - 0.6*smax)); M = U < prob;
//   j[c] = FIRST argmax over unselected d of S_new[c,:];
//   perm = where(M, j, idx); then sequential last-wins scatter perm[j[c]]=c;
//   valid = any(M) && any(!M) else identity.
// ---------------------------------------------------------------------------
__global__ __launch_bounds__(256) void k_perm(const float* __restrict__ s_score,
                                              const float* __restrict__ U,
                                              const float* __restrict__ S_new,
                                              int* __restrict__ perm_g) {
    const int b = blockIdx.x;
    const int c = threadIdx.x;
    __shared__ float red[256];
    __shared__ int m[256];
    __shared__ int jj[256];
    __shared__ int perm[256];

    const float s = s_score[b * 256 + c];
    red[c] = s; __syncthreads();
    for (int off = 128; off > 0; off >>= 1) {
        if (c < off) red[c] = fmaxf(red[c], red[c + off]);
        __syncthreads();
    }
    const float smax = red[0];
    __syncthreads();

    const float prob = 1.f / (1.f + expf(-5.f * (s - 0.6f * smax)));
    const int mi = (U[b * 256 + c] < prob) ? 1 : 0;
    m[c] = mi;
    red[c] = (float)mi;
    __syncthreads();
    for (int off = 128; off > 0; off >>= 1) {
        if (c < off) red[c] += red[c + off];
        __syncthreads();
    }
    const int cnt = (int)red[0];

    // first-max argmax over unselected columns
    float best = -INFINITY; int bj = 0;
    const float* row = S_new + c * 256;
    for (int d2 = 0; d2 < 256; ++d2) {
        const float v = row[d2];
        if (!m[d2] && v > best) { best = v; bj = d2; }
    }
    jj[c] = bj;
    perm[c] = mi ? bj : c;
    __syncthreads();

    const int valid = (cnt > 0) && (cnt < 256);
    if (c == 0 && valid) {
        for (int q = 0; q < 256; ++q)
            if (m[q]) perm[jj[q]] = q;      // last-wins, ascending q
    }
    __syncthreads();
    perm_g[b * 256 + c] = valid ? perm[c] : c;
}

// ---------------------------------------------------------------------------
// Kernel 5: gather planes. out[b,c,:,:] = F[b, perm[b,c], :, :]
// ---------------------------------------------------------------------------
__global__ __launch_bounds__(256) void k_gather(const float* __restrict__ F,
                                                const int* __restrict__ perm_g,
                                                float* __restrict__ out) {
    const int plane = blockIdx.x;            // b*256 + c
    const int b = plane >> 8;
    const int p = perm_g[plane];
    const float4* src = (const float4*)(F + ((size_t)b * 256 + p) * NN);
    float4* dst = (float4*)(out + (size_t)plane * NN);
    const int tid = threadIdx.x;
    #pragma unroll
    for (int q = 0; q < 4; ++q) dst[tid + q * 256] = src[tid + q * 256];
}

// ---------------------------------------------------------------------------
extern "C" void kernel_launch(void* const* d_in, const int* in_sizes, int n_in,
                              void* d_out, int out_size, void* d_ws, size_t ws_size,
                              hipStream_t stream) {
    const float* F = (const float*)d_in[0];
    const float* S = (const float*)d_in[1];
    const float* U = (const float*)d_in[2];
    float* out = (float*)d_out;

    char* ws = (char*)d_ws;
    size_t off = 0;
    float* S_part  = (float*)(ws + off); off += (size_t)64 * 10 * 4096 * 4;  // 10.49 MB
    float* inv_nrm = (float*)(ws + off); off += 8192 * 4;
    float* s_score = (float*)(ws + off); off += 8192 * 4;
    float* S_new   = (float*)(ws + off); off += 65536 * 4;
    int*   perm    = (int*)  (ws + off); off += 8192 * 4;

    k_prep  <<<8192, 256, 0, stream>>>(F, inv_nrm, s_score);
    k_gram  <<<dim3(10, 64), 256, 0, stream>>>(F, inv_nrm, S_part);
    k_snew  <<<256, 256, 0, stream>>>(S_part, S, S_new);
    k_perm  <<<32, 256, 0, stream>>>(s_score, U, S_new, perm);
    k_gather<<<8192, 256, 0, stream>>>(F, perm, out);
}

// Round 4
// 489.207 us; speedup vs baseline: 1.0162x; 1.0162x over previous
//
#include <hip/hip_runtime.h>
#include <math.h>

// Problem constants
#define BB 32
#define CC 256
#define HH 64
#define WW 64
#define NN 4096   // H*W

__inline__ __device__ float waveReduceSum(float v) {
    #pragma unroll
    for (int off = 32; off > 0; off >>= 1) v += __shfl_xor(v, off);
    return v;
}
__inline__ __device__ float waveReduceMax(float v) {
    #pragma unroll
    for (int off = 32; off > 0; off >>= 1) v = fmaxf(v, __shfl_xor(v, off));
    return v;
}

// ---------------------------------------------------------------------------
// Kernel 1: per-(b,c) plane prep (unchanged from R3 — passed exact).
// ---------------------------------------------------------------------------
__global__ __launch_bounds__(256) void k_prep(const float* __restrict__ F,
                                              float* __restrict__ inv_norm,
                                              float* __restrict__ s_score) {
    const int plane = blockIdx.x;                 // b*256 + c
    const int tid = threadIdx.x;
    __shared__ float bin[4096];
    __shared__ float rowsum[4096];
    __shared__ float swS[4], swQ[4], swM[4];

    const float4* src = (const float4*)(F + (size_t)plane * NN);
    float4 v[4];
    float sum = 0.f, ssq = 0.f, mx = -INFINITY;
    #pragma unroll
    for (int q = 0; q < 4; ++q) {
        v[q] = src[tid + q * 256];
        sum += v[q].x + v[q].y + v[q].z + v[q].w;
        ssq += v[q].x * v[q].x + v[q].y * v[q].y + v[q].z * v[q].z + v[q].w * v[q].w;
        mx = fmaxf(mx, fmaxf(fmaxf(v[q].x, v[q].y), fmaxf(v[q].z, v[q].w)));
    }
    sum = waveReduceSum(sum);
    ssq = waveReduceSum(ssq);
    mx  = waveReduceMax(mx);
    const int w = tid >> 6, ln = tid & 63;
    if (ln == 0) { swS[w] = sum; swQ[w] = ssq; swM[w] = mx; }
    __syncthreads();
    if (tid == 0) {
        swS[0] = swS[0] + swS[1] + swS[2] + swS[3];
        swQ[0] = swQ[0] + swQ[1] + swQ[2] + swQ[3];
        swM[0] = fmaxf(fmaxf(swM[0], swM[1]), fmaxf(swM[2], swM[3]));
    }
    __syncthreads();
    const float totsum = swS[0];
    const float totssq = swQ[0];
    const float thr = 0.6f * swM[0];

    #pragma unroll
    for (int q = 0; q < 4; ++q) {
        const int base = (tid + q * 256) * 4;
        bin[base + 0] = (v[q].x >= thr) ? 1.f : 0.f;
        bin[base + 1] = (v[q].y >= thr) ? 1.f : 0.f;
        bin[base + 2] = (v[q].z >= thr) ? 1.f : 0.f;
        bin[base + 3] = (v[q].w >= thr) ? 1.f : 0.f;
    }
    __syncthreads();

    #pragma unroll
    for (int q = 0; q < 16; ++q) {
        const int p = tid + q * 256;
        const int h = p >> 6, x = p & 63;
        float s5 = 0.f;
        #pragma unroll
        for (int dw = -2; dw <= 2; ++dw) {
            const int xx = x + dw;
            if (xx >= 0 && xx < 64) s5 += bin[h * 64 + xx];
        }
        rowsum[p] = s5;
    }
    __syncthreads();

    int cge = 0;
    #pragma unroll
    for (int q = 0; q < 16; ++q) {
        const int p = tid + q * 256;
        const int h = p >> 6, x = p & 63;
        float cnt = 0.f;
        #pragma unroll
        for (int dh = -2; dh <= 2; ++dh) {
            const int hh = h + dh;
            if (hh >= 0 && hh < 64) cnt += rowsum[hh * 64 + x];
        }
        if (cnt >= 12.5f) cge++;   // density >= 0.5 exactly (integer counts)
    }
    float cf = waveReduceSum((float)cge);
    __syncthreads();
    if (ln == 0) swS[w] = cf;
    __syncthreads();
    if (tid == 0) {
        const float total = swS[0] + swS[1] + swS[2] + swS[3];
        const float d = total / 4096.f;
        const float a = 1.f / (1.f + expf(-(totsum / 4096.f)));
        s_score[plane] = sqrtf(a) * sqrtf(d);
        inv_norm[plane] = 1.f / (sqrtf(totssq) + 1e-6f);
    }
}

// ---------------------------------------------------------------------------
// Kernel 2: gram partials, split-K x nch (nch=4 normally; 2 if ws small).
// blockIdx.y = bc in [0, 32*nch): b = bc>>csh, chunk = bc&(nch-1).
// K chunk = 4096>>csh; s-loop iters = 128>>csh.
// Output: S_part[bc*10 + t][64][64] f32.
// ---------------------------------------------------------------------------
__global__ __launch_bounds__(256) void k_gram(const float* __restrict__ F,
                                              const float* __restrict__ inv_norm,
                                              float* __restrict__ S_part,
                                              int csh) {
    static const int TI[10] = {0,0,0,0,1,1,1,2,2,3};
    static const int TJ[10] = {0,1,2,3,1,2,3,2,3,3};
    const int t  = blockIdx.x;       // 0..9 tile
    const int bc = blockIdx.y;       // 0..32*nch-1
    const int b = bc >> csh, chunk = bc & ((1 << csh) - 1);
    const int ti = TI[t], tj = TJ[t];
    const int k0 = chunk << (12 - csh);          // chunk * (4096>>csh)
    const int iters = 128 >> csh;                // (4096>>csh)/32

    __shared__ float As[32][68];     // [kk][row]
    __shared__ float Bs[32][68];

    const int tid = threadIdx.x;
    const int lrow = tid >> 2;       // 0..63
    const int kgrp = tid & 3;        // 0..3 (8 floats each)
    const float* Fb = F + (size_t)b * CC * NN;
    const float scaleA = inv_norm[b * CC + ti * 64 + lrow];
    const float scaleB = inv_norm[b * CC + tj * 64 + lrow];
    const float* gA = Fb + (size_t)(ti * 64 + lrow) * NN + k0 + kgrp * 8;
    const float* gB = Fb + (size_t)(tj * 64 + lrow) * NN + k0 + kgrp * 8;

    const int r0 = (tid >> 4) << 2;  // row quad
    const int c0 = (tid & 15) << 2;  // col quad

    float accL2[16];
    #pragma unroll
    for (int e = 0; e < 16; ++e) accL2[e] = 0.f;

    for (int s = 0; s < iters; ++s) {
        const float4 a0 = *(const float4*)(gA);
        const float4 a1 = *(const float4*)(gA + 4);
        const float4 b0 = *(const float4*)(gB);
        const float4 b1 = *(const float4*)(gB + 4);
        __syncthreads();
        const int kb = kgrp * 8;
        As[kb + 0][lrow] = a0.x * scaleA; As[kb + 1][lrow] = a0.y * scaleA;
        As[kb + 2][lrow] = a0.z * scaleA; As[kb + 3][lrow] = a0.w * scaleA;
        As[kb + 4][lrow] = a1.x * scaleA; As[kb + 5][lrow] = a1.y * scaleA;
        As[kb + 6][lrow] = a1.z * scaleA; As[kb + 7][lrow] = a1.w * scaleA;
        Bs[kb + 0][lrow] = b0.x * scaleB; Bs[kb + 1][lrow] = b0.y * scaleB;
        Bs[kb + 2][lrow] = b0.z * scaleB; Bs[kb + 3][lrow] = b0.w * scaleB;
        Bs[kb + 4][lrow] = b1.x * scaleB; Bs[kb + 5][lrow] = b1.y * scaleB;
        Bs[kb + 6][lrow] = b1.z * scaleB; Bs[kb + 7][lrow] = b1.w * scaleB;
        __syncthreads();

        float accL1[16];
        #pragma unroll
        for (int e = 0; e < 16; ++e) accL1[e] = 0.f;
        #pragma unroll
        for (int kk = 0; kk < 32; ++kk) {
            const float4 av = *(const float4*)&As[kk][r0];
            const float4 bv = *(const float4*)&Bs[kk][c0];
            const float ar[4] = {av.x, av.y, av.z, av.w};
            const float br[4] = {bv.x, bv.y, bv.z, bv.w};
            #pragma unroll
            for (int rr = 0; rr < 4; ++rr)
                #pragma unroll
                for (int cc = 0; cc < 4; ++cc)
                    accL1[rr * 4 + cc] += ar[rr] * br[cc];
        }
        #pragma unroll
        for (int e = 0; e < 16; ++e) accL2[e] += accL1[e];
        gA += 32; gB += 32;
    }

    float* dst = S_part + (size_t)(bc * 10 + t) * 4096;
    #pragma unroll
    for (int rr = 0; rr < 4; ++rr)
        #pragma unroll
        for (int cc = 0; cc < 4; ++cc)
            dst[(r0 + rr) * 64 + (c0 + cc)] = accL2[rr * 4 + cc];
}

// ---------------------------------------------------------------------------
// Kernel 3: reduce npart partials (f64, deterministic), EMA, symmetrize.
// ---------------------------------------------------------------------------
__global__ __launch_bounds__(256) void k_snew(const float* __restrict__ S_part,
                                              const float* __restrict__ S_old,
                                              float* __restrict__ S_new,
                                              int npart) {
    const int c = blockIdx.x;
    const int d = threadIdx.x;
    if (d < c) return;   // upper triangle incl diagonal
    static const int tmap[16] = {0,1,2,3, -1,4,5,6, -1,-1,7,8, -1,-1,-1,9};
    const int t = tmap[((c >> 6) << 2) | (d >> 6)];
    const int r = c & 63, col = d & 63;
    const float* base = S_part + (size_t)t * 4096 + r * 64 + col;
    double sum = 0.0;
    for (int p = 0; p < npart; ++p) sum += (double)base[(size_t)p * 40960];
    const float sb = (float)(sum * (1.0 / 32.0));   // mean over B=32
    S_new[c * 256 + d] = 0.999f * S_old[c * 256 + d] + 0.001f * sb;
    if (d != c)
        S_new[d * 256 + c] = 0.999f * S_old[d * 256 + c] + 0.001f * sb;
}

// ---------------------------------------------------------------------------
// Kernel 4: per-sample mask + permutation (unchanged).
// ---------------------------------------------------------------------------
__global__ __launch_bounds__(256) void k_perm(const float* __restrict__ s_score,
                                              const float* __restrict__ U,
                                              const float* __restrict__ S_new,
                                              int* __restrict__ perm_g) {
    const int b = blockIdx.x;
    const int c = threadIdx.x;
    __shared__ float red[256];
    __shared__ int m[256];
    __shared__ int jj[256];
    __shared__ int perm[256];

    const float s = s_score[b * 256 + c];
    red[c] = s; __syncthreads();
    for (int off = 128; off > 0; off >>= 1) {
        if (c < off) red[c] = fmaxf(red[c], red[c + off]);
        __syncthreads();
    }
    const float smax = red[0];
    __syncthreads();

    const float prob = 1.f / (1.f + expf(-5.f * (s - 0.6f * smax)));
    const int mi = (U[b * 256 + c] < prob) ? 1 : 0;
    m[c] = mi;
    red[c] = (float)mi;
    __syncthreads();
    for (int off = 128; off > 0; off >>= 1) {
        if (c < off) red[c] += red[c + off];
        __syncthreads();
    }
    const int cnt = (int)red[0];

    float best = -INFINITY; int bj = 0;
    const float* row = S_new + c * 256;
    for (int d2 = 0; d2 < 256; ++d2) {
        const float v = row[d2];
        if (!m[d2] && v > best) { best = v; bj = d2; }
    }
    jj[c] = bj;
    perm[c] = mi ? bj : c;
    __syncthreads();

    const int valid = (cnt > 0) && (cnt < 256);
    if (c == 0 && valid) {
        for (int q = 0; q < 256; ++q)
            if (m[q]) perm[jj[q]] = q;      // last-wins, ascending q
    }
    __syncthreads();
    perm_g[b * 256 + c] = valid ? perm[c] : c;
}

// ---------------------------------------------------------------------------
// Kernel 5: gather planes (unchanged).
// ---------------------------------------------------------------------------
__global__ __launch_bounds__(256) void k_gather(const float* __restrict__ F,
                                                const int* __restrict__ perm_g,
                                                float* __restrict__ out) {
    const int plane = blockIdx.x;            // b*256 + c
    const int b = plane >> 8;
    const int p = perm_g[plane];
    const float4* src = (const float4*)(F + ((size_t)b * 256 + p) * NN);
    float4* dst = (float4*)(out + (size_t)plane * NN);
    const int tid = threadIdx.x;
    #pragma unroll
    for (int q = 0; q < 4; ++q) dst[tid + q * 256] = src[tid + q * 256];
}

// ---------------------------------------------------------------------------
extern "C" void kernel_launch(void* const* d_in, const int* in_sizes, int n_in,
                              void* d_out, int out_size, void* d_ws, size_t ws_size,
                              hipStream_t stream) {
    const float* F = (const float*)d_in[0];
    const float* S = (const float*)d_in[1];
    const float* U = (const float*)d_in[2];
    float* out = (float*)d_out;

    // split-K factor: 4 chunks needs 21.4 MB of partials; fall back if ws small.
    const size_t need4 = (size_t)128 * 10 * 4096 * 4 + (3 * 8192 + 65536) * 4 + (1 << 16);
    const int csh = (ws_size >= need4) ? 2 : 1;       // nch = 1<<csh
    const int nch = 1 << csh;
    const int npart = 32 * nch;

    char* ws = (char*)d_ws;
    size_t off = 0;
    float* S_part  = (float*)(ws + off); off += (size_t)npart * 10 * 4096 * 4;
    float* inv_nrm = (float*)(ws + off); off += 8192 * 4;
    float* s_score = (float*)(ws + off); off += 8192 * 4;
    float* S_new   = (float*)(ws + off); off += 65536 * 4;
    int*   perm    = (int*)  (ws + off); off += 8192 * 4;

    k_prep  <<<8192, 256, 0, stream>>>(F, inv_nrm, s_score);
    k_gram  <<<dim3(10, npart), 256, 0, stream>>>(F, inv_nrm, S_part, csh);
    k_snew  <<<256, 256, 0, stream>>>(S_part, S, S_new, npart);
    k_perm  <<<32, 256, 0, stream>>>(s_score, U, S_new, perm);
    k_gather<<<8192, 256, 0, stream>>>(F, perm, out);
}